// Round 4
// baseline (40925.662 us; speedup 1.0000x reference)
//
#include <hip/hip_runtime.h>

// Problem constants (fixed by setup_inputs): x (4, 64, 8192, 1) fp32, k=9, dilation=1
#define BB 4
#define DD 64
#define NN 8192
#define KK 9
#define SPL 2       // column splits (grid.y)
#define MB 64       // rows per block
#define NT 64       // cols per tile
#define TM 4        // thread tile rows
#define TN 4        // thread tile cols

typedef unsigned long long u64;

// ---------------- Kernel 1: L2-normalize + pack to (b*N+n, 64) + per-point sq ----
// MUST stay bit-identical to rounds 1-2: the downstream ranking is sensitive to
// the exact fp32 bits of xnT and sq.
__global__ __launch_bounds__(256) void knorm_kernel(const float* __restrict__ x,
                                                    float* __restrict__ xnT,
                                                    float* __restrict__ sq) {
    int t = blockIdx.x * 256 + threadIdx.x;      // row id 0..B*N-1
    int b = t >> 13;                             // / 8192
    int n = t & (NN - 1);
    const float* xb = x + (size_t)b * DD * NN + n;
    float v[DD];
    float ss = 0.0f;
#pragma unroll
    for (int d = 0; d < DD; ++d) {
        v[d] = xb[(size_t)d * NN];               // coalesced across lanes
        ss = fmaf(v[d], v[d], ss);
    }
    float inv = 1.0f / fmaxf(sqrtf(ss), 1e-12f);
    float s2 = 0.0f;
#pragma unroll
    for (int d = 0; d < DD; ++d) {
        float xv = v[d] * inv;
        v[d] = xv;
        s2 = fmaf(xv, xv, s2);
    }
    float4* o4 = reinterpret_cast<float4*>(xnT + (size_t)t * DD);
#pragma unroll
    for (int d = 0; d < DD; d += 4) {
        o4[d >> 2] = make_float4(v[d], v[d + 1], v[d + 2], v[d + 3]);
    }
    sq[t] = s2;
}

// u64 ascending insert into sorted kd[KK]; strict-less reproduces top_k's
// lower-index-first tie rule (index lives in the low 32 bits). Exact integer
// ops -> selection result is independent of visit/merge order.
#define INSERT9(kdrow, cndv)                                   \
    do {                                                       \
        u64 _c = (cndv);                                       \
        _Pragma("unroll")                                      \
        for (int _m = 0; _m < KK; ++_m) {                      \
            bool _sw = _c < kdrow[_m];                         \
            u64 _lo = _sw ? _c : kdrow[_m];                    \
            u64 _hi = _sw ? kdrow[_m] : _c;                    \
            kdrow[_m] = _lo;                                   \
            _c = _hi;                                          \
        }                                                      \
    } while (0)

// ---------------- Kernel 2: register-tiled distance GEMM + fused top-9 ----------
// Block: 256 threads = 16x16, thread tile TMxTN, block tile 64 rows x 64 cols,
// K=64 fully staged in LDS transposed to [k][m]/[k][n] (one ds_read_b128 per
// fragment; A read is 16-lane broadcast, B read is 2-way bank alias = free).
//
// NUMERICS CONTRACT (round-3 post-mortem): the dot product uses FOUR chains,
// chain c accumulating k === c (mod 4) in increasing k, combined as
// (a0+a1)+(a2+a3) -- bit-identical to the round-1/2 kernel that passes on this
// dataset. Do NOT reassociate: rank-boundary gaps are ~8e-3 but a different
// summation order flips ~1 boundary per dataset (absmax 704 in round 3).
__global__ __launch_bounds__(256, 2) void kdist_kernel(const float* __restrict__ xnT,
                                                       const float* __restrict__ sq,
                                                       u64* __restrict__ cand) {
    __shared__ __align__(16) char smemPool[(DD * MB + DD * NT + NT) * 4];
    float (*As)[MB] = (float (*)[MB])smemPool;                       // [k][m] 16 KB
    float (*Bs)[NT] = (float (*)[NT])(smemPool + DD * MB * 4);       // [k][n] 16 KB
    float* sqs = (float*)(smemPool + (DD * MB + DD * NT) * 4);       // 256 B
    u64* mrg = (u64*)smemPool;                                       // epilogue alias, 18 KB

    const int t = threadIdx.x;
    const int tx = t & 15;
    const int ty = t >> 4;
    const int bx = blockIdx.x;            // 0..511
    const int b = bx >> 7;                // 128 row-blocks per batch
    const int rowBase = (bx & 127) * MB;
    const int s = blockIdx.y;             // split
    const int colBase0 = s * (NN / SPL);

    const float* __restrict__ Xb = xnT + (size_t)b * NN * DD;
    const float* __restrict__ sqb = sq + (size_t)b * NN;

    // ---- stage A-tile (64 rows x 64 k), transposed to [k][m], once per block ----
    {
        int r = t >> 2, dq = t & 3;       // r: row in tile, dq: 16-k chunk
        const float4* src = (const float4*)(Xb + (size_t)(rowBase + r) * DD + dq * 16);
#pragma unroll
        for (int q = 0; q < 4; ++q) {
            float4 f = src[q];
            int d0 = dq * 16 + q * 4;
            As[d0 + 0][r] = f.x;
            As[d0 + 1][r] = f.y;
            As[d0 + 2][r] = f.z;
            As[d0 + 3][r] = f.w;
        }
    }

    u64 kd[TM][KK];
#pragma unroll
    for (int i = 0; i < TM; ++i)
#pragma unroll
        for (int m = 0; m < KK; ++m) kd[i][m] = ~0ULL;

    const int NTILES = (NN / SPL) / NT;   // 64
#pragma unroll 1
    for (int tile = 0; tile < NTILES; ++tile) {
        const int colBase = colBase0 + tile * NT;
        __syncthreads();                  // Bs reads from previous tile done
        // ---- stage B-tile (64 cols x 64 k) transposed, + sq slice ----
        {
            int r = t >> 2, dq = t & 3;
            const float4* src = (const float4*)(Xb + (size_t)(colBase + r) * DD + dq * 16);
#pragma unroll
            for (int q = 0; q < 4; ++q) {
                float4 f = src[q];
                int d0 = dq * 16 + q * 4;
                Bs[d0 + 0][r] = f.x;
                Bs[d0 + 1][r] = f.y;
                Bs[d0 + 2][r] = f.z;
                Bs[d0 + 3][r] = f.w;
            }
            if (t < 16) ((float4*)sqs)[t] = *(const float4*)(sqb + colBase + t * 4);
        }
        __syncthreads();

        // ---- 4x4 register tile, 4 accumulation chains (k mod 4), K=64 ----
        float acc0[TM][TN], acc1[TM][TN], acc2[TM][TN], acc3[TM][TN];
#pragma unroll
        for (int i = 0; i < TM; ++i)
#pragma unroll
            for (int j = 0; j < TN; ++j) {
                acc0[i][j] = 0.0f; acc1[i][j] = 0.0f;
                acc2[i][j] = 0.0f; acc3[i][j] = 0.0f;
            }

#define KSTEP(ACC, KIDX)                                                        \
        do {                                                                    \
            const int kk_ = (KIDX);                                             \
            float4 a4 = *(const float4*)&As[kk_][ty * TM];                      \
            float4 b4 = *(const float4*)&Bs[kk_][tx * TN];                      \
            float a_[TM] = {a4.x, a4.y, a4.z, a4.w};                           \
            float b_[TN] = {b4.x, b4.y, b4.z, b4.w};                           \
            _Pragma("unroll")                                                   \
            for (int i = 0; i < TM; ++i)                                        \
                _Pragma("unroll")                                               \
                for (int j = 0; j < TN; ++j)                                    \
                    ACC[i][j] = fmaf(a_[i], b_[j], ACC[i][j]);                  \
        } while (0)

#pragma unroll
        for (int k4 = 0; k4 < DD / 4; ++k4) {
            KSTEP(acc0, 4 * k4 + 0);
            KSTEP(acc1, 4 * k4 + 1);
            KSTEP(acc2, 4 * k4 + 2);
            KSTEP(acc3, 4 * k4 + 3);
        }
#undef KSTEP

        // ---- fused selection: key = sq_j - 2*dot (monotone with ref distance) ----
#pragma unroll
        for (int i = 0; i < TM; ++i) {
#pragma unroll
            for (int j = 0; j < TN; ++j) {
                float dot = (acc0[i][j] + acc1[i][j]) + (acc2[i][j] + acc3[i][j]);
                float key = fmaf(-2.0f, dot, sqs[tx * TN + j]);
                unsigned ub = __float_as_uint(key);
                ub ^= (0x80000000u | (unsigned)((int)ub >> 31));   // order-preserving
                u64 cnd = ((u64)ub << 32) | (unsigned)(colBase + tx * TN + j);
                if (cnd < kd[i][KK - 1]) INSERT9(kd[i], cnd);
            }
        }
    }

    // ---- per-row merge across the 16 thread-columns, 16 rows per phase ----
#pragma unroll 1
    for (int p = 0; p < 4; ++p) {
        __syncthreads();
        if ((ty >> 2) == p) {
            int lr0 = (ty & 3) * TM;      // local row 0..12
#pragma unroll
            for (int i = 0; i < TM; ++i)
#pragma unroll
                for (int m = 0; m < KK; ++m)
                    mrg[((lr0 + i) * 16 + tx) * KK + m] = kd[i][m];
        }
        __syncthreads();
        if (t < 16) {
            u64 md[KK];
#pragma unroll
            for (int m = 0; m < KK; ++m) md[m] = ~0ULL;
            const u64* c = mrg + t * (16 * KK);
            for (int q = 0; q < 16 * KK; ++q) {
                u64 cnd = c[q];
                if (cnd < md[KK - 1]) INSERT9(md, cnd);
            }
            int n = rowBase + p * 16 + t;
            u64* o = cand + ((size_t)(b * NN + n) * SPL + s) * KK;
#pragma unroll
            for (int m = 0; m < KK; ++m) o[m] = md[m];
        }
    }
}

// ---------------- Kernel 3: merge splits, emit edge_index -----------------------
__global__ __launch_bounds__(256) void kmerge_kernel(const u64* __restrict__ cand,
                                                     int* __restrict__ out) {
    int t = blockIdx.x * 256 + threadIdx.x;      // row id 0..B*N-1
    const u64* c = cand + (size_t)t * (SPL * KK);
    u64 kd[KK];
#pragma unroll
    for (int m = 0; m < KK; ++m) kd[m] = ~0ULL;
#pragma unroll
    for (int q = 0; q < SPL * KK; ++q) {
        u64 cnd = c[q];
        if (cnd < kd[KK - 1]) INSERT9(kd, cnd);
    }
    int n = t & (NN - 1);
    int* out0 = out + (size_t)t * KK;                           // nn_idx part
    int* out1 = out + (size_t)BB * NN * KK + (size_t)t * KK;    // center part
#pragma unroll
    for (int m = 0; m < KK; ++m) {
        out0[m] = (int)(kd[m] & 0xFFFFFFFFULL);
        out1[m] = n;
    }
}

extern "C" void kernel_launch(void* const* d_in, const int* in_sizes, int n_in,
                              void* d_out, int out_size, void* d_ws, size_t ws_size,
                              hipStream_t stream) {
    const float* x = (const float*)d_in[0];
    // d_in[1] (k) and d_in[2] (dilation) are fixed: 9, 1.
    int* out = (int*)d_out;

    // Workspace layout
    char* ws = (char*)d_ws;
    float* xnT = (float*)ws;                                     // 8 MB
    float* sq = (float*)(ws + (size_t)BB * NN * DD * 4);         // 128 KB
    u64* cand = (u64*)(ws + (size_t)BB * NN * DD * 4 + (size_t)BB * NN * 4);  // 4.7 MB

    knorm_kernel<<<dim3(BB * NN / 256), dim3(256), 0, stream>>>(x, xnT, sq);
    kdist_kernel<<<dim3(BB * (NN / MB), SPL), dim3(256), 0, stream>>>(xnT, sq, cand);
    kmerge_kernel<<<dim3(BB * NN / 256), dim3(256), 0, stream>>>(cand, out);
}

// Round 5
// 1135.829 us; speedup vs baseline: 36.0315x; 36.0315x over previous
//
#include <hip/hip_runtime.h>

// Problem constants (fixed by setup_inputs): x (4, 64, 8192, 1) fp32, k=9, dilation=1
#define BB 4
#define DD 64
#define NN 8192
#define KK 9

typedef unsigned long long u64;

// ---------------- Kernel 1: L2-normalize + pack to (b*N+n, 64) + per-point sq ----
// MUST stay bit-identical across rounds: downstream ranking is sensitive to the
// exact fp32 bits of xnT and sq.
__global__ __launch_bounds__(256) void knorm_kernel(const float* __restrict__ x,
                                                    float* __restrict__ xnT,
                                                    float* __restrict__ sq) {
    int t = blockIdx.x * 256 + threadIdx.x;      // row id 0..B*N-1
    int b = t >> 13;                             // / 8192
    int n = t & (NN - 1);
    const float* xb = x + (size_t)b * DD * NN + n;
    float v[DD];
    float ss = 0.0f;
#pragma unroll
    for (int d = 0; d < DD; ++d) {
        v[d] = xb[(size_t)d * NN];               // coalesced across lanes
        ss = fmaf(v[d], v[d], ss);
    }
    float inv = 1.0f / fmaxf(sqrtf(ss), 1e-12f);
    float s2 = 0.0f;
#pragma unroll
    for (int d = 0; d < DD; ++d) {
        float xv = v[d] * inv;
        v[d] = xv;
        s2 = fmaf(xv, xv, s2);
    }
    float4* o4 = reinterpret_cast<float4*>(xnT + (size_t)t * DD);
#pragma unroll
    for (int d = 0; d < DD; d += 4) {
        o4[d >> 2] = make_float4(v[d], v[d + 1], v[d + 2], v[d + 3]);
    }
    sq[t] = s2;
}

// u64 ascending insert; strict-less reproduces top_k's lower-index-first tie
// rule (index in low 32 bits). Exact integer ops -> order-independent selection.
#define INSERT9(kdrow, cndv)                                   \
    do {                                                       \
        u64 _c = (cndv);                                       \
        _Pragma("unroll")                                      \
        for (int _m = 0; _m < KK; ++_m) {                      \
            bool _sw = _c < kdrow[_m];                         \
            u64 _lo = _sw ? _c : kdrow[_m];                    \
            u64 _hi = _sw ? kdrow[_m] : _c;                    \
            kdrow[_m] = _lo;                                   \
            _c = _hi;                                          \
        }                                                      \
    } while (0)

// ---------------- Kernel 2: fused distance scan + per-split top-9 ---------------
// One thread per row; all lanes share a wave-uniform column j -> column data and
// sq[j] lower to SGPR scalar loads (verified round 2: SGPR=64, per-lane traffic
// was row-only). The row is loaded ONCE before the loop; the asm memory clobber
// inside the loop makes rematerializing (or sinking) those loads ILLEGAL, so the
// row must stay in VGPRs. Live set ~105 regs < the 128-reg occupancy step, so
// the allocator has no reason to spill (round 4's spill storm needed ~150).
//
// NUMERICS CONTRACT: four chains, chain c accumulates k===c (mod 4) in
// increasing k, combined (a0+a1)+(a2+a3) -- bit-identical to rounds 1/2/4.
// Do NOT reassociate (round 3: one reassociation flipped a rank boundary).
template <int S>
__global__ __launch_bounds__(256, 2) void kdist_kernel(const float* __restrict__ xnT,
                                                       const float* __restrict__ sq,
                                                       u64* __restrict__ cand) {
    const int rb = blockIdx.x;                   // 0..127 (32 rowblocks per batch)
    const int b = rb >> 5;                       // uniform (from blockIdx only)
    const int nbase = (rb & 31) * 256;
    const int n = nbase + threadIdx.x;
    const int s = blockIdx.y;                    // split id
    const int jcount = NN / S;
    const int j0 = s * jcount;
    const int j1 = j0 + jcount;

    const float* __restrict__ Bb = xnT + ((size_t)b * NN) * DD;  // uniform base
    const float* __restrict__ sqb = sq + (size_t)b * NN;         // uniform base

    // Load this thread's row once. Kept in VGPRs by the loop's memory clobber.
    float ar[DD];
    {
        const float4* a4 = reinterpret_cast<const float4*>(Bb + (size_t)n * DD);
#pragma unroll
        for (int d = 0; d < DD; d += 4) {
            float4 f = a4[d >> 2];
            ar[d] = f.x; ar[d + 1] = f.y; ar[d + 2] = f.z; ar[d + 3] = f.w;
        }
    }

    // Top-9 as sorted ascending packed u64: (sortable key bits << 32) | j.
    u64 kd[KK];
#pragma unroll
    for (int m = 0; m < KK; ++m) kd[m] = ~0ULL;

#pragma unroll 1
    for (int j = j0; j < j1; ++j) {
        // Opaque memory clobber: reloading ar[] after this point would not be
        // semantics-preserving, so the compiler must keep it in registers.
        asm volatile("" ::: "memory");

        const float4* bc4 = reinterpret_cast<const float4*>(Bb + (size_t)j * DD); // uniform
        float a0 = 0.0f, a1 = 0.0f, a2 = 0.0f, a3 = 0.0f;
#pragma unroll
        for (int d4 = 0; d4 < DD / 4; ++d4) {
            float4 f = bc4[d4];
            a0 = fmaf(ar[4 * d4 + 0], f.x, a0);
            a1 = fmaf(ar[4 * d4 + 1], f.y, a1);
            a2 = fmaf(ar[4 * d4 + 2], f.z, a2);
            a3 = fmaf(ar[4 * d4 + 3], f.w, a3);
        }
        float dot = (a0 + a1) + (a2 + a3);
        float key = fmaf(-2.0f, dot, sqb[j]);    // sq_j - 2*dot (sq_i is per-row const)
        unsigned ub = __float_as_uint(key);
        ub ^= (0x80000000u | (unsigned)((int)ub >> 31));   // order-preserving map
        u64 cnd = ((u64)ub << 32) | (unsigned)j;
        if (cnd < kd[KK - 1]) INSERT9(kd, cnd);
    }

    u64* out = cand + ((size_t)(b * NN + n) * S + s) * KK;
#pragma unroll
    for (int m = 0; m < KK; ++m) out[m] = kd[m];
}

// ---------------- Kernel 3: merge splits, emit edge_index -----------------------
template <int S>
__global__ __launch_bounds__(256) void kmerge_kernel(const u64* __restrict__ cand,
                                                     int* __restrict__ out) {
    int t = blockIdx.x * 256 + threadIdx.x;      // row id 0..B*N-1
    const u64* c = cand + (size_t)t * (S * KK);
    u64 kd[KK];
#pragma unroll
    for (int m = 0; m < KK; ++m) kd[m] = ~0ULL;
#pragma unroll
    for (int q = 0; q < S * KK; ++q) {
        u64 cnd = c[q];
        if (cnd < kd[KK - 1]) INSERT9(kd, cnd);
    }
    int n = t & (NN - 1);
    int* out0 = out + (size_t)t * KK;                           // nn_idx part
    int* out1 = out + (size_t)BB * NN * KK + (size_t)t * KK;    // center part
#pragma unroll
    for (int m = 0; m < KK; ++m) {
        out0[m] = (int)(kd[m] & 0xFFFFFFFFULL);
        out1[m] = n;
    }
}

extern "C" void kernel_launch(void* const* d_in, const int* in_sizes, int n_in,
                              void* d_out, int out_size, void* d_ws, size_t ws_size,
                              hipStream_t stream) {
    const float* x = (const float*)d_in[0];
    // d_in[1] (k) and d_in[2] (dilation) are fixed: 9, 1.
    int* out = (int*)d_out;

    // Workspace layout
    char* ws = (char*)d_ws;
    float* xnT = (float*)ws;                                     // 8 MB
    float* sq = (float*)(ws + (size_t)BB * NN * DD * 4);         // 128 KB
    u64* cand = (u64*)(ws + (size_t)BB * NN * DD * 4 + (size_t)BB * NN * 4);

    const size_t base = (size_t)BB * NN * DD * 4 + (size_t)BB * NN * 4;
    const size_t need8 = base + (size_t)BB * NN * 8 * KK * 8;    // ~27 MB with S=8

    knorm_kernel<<<dim3(BB * NN / 256), dim3(256), 0, stream>>>(x, xnT, sq);
    if (ws_size >= need8) {
        // S=8: 1024 blocks = exactly 4 blocks/CU resident (16 waves/CU at <=128 VGPR)
        kdist_kernel<8><<<dim3(BB * NN / 256, 8), dim3(256), 0, stream>>>(xnT, sq, cand);
        kmerge_kernel<8><<<dim3(BB * NN / 256), dim3(256), 0, stream>>>(cand, out);
    } else {
        kdist_kernel<4><<<dim3(BB * NN / 256, 4), dim3(256), 0, stream>>>(xnT, sq, cand);
        kmerge_kernel<4><<<dim3(BB * NN / 256), dim3(256), 0, stream>>>(cand, out);
    }
}